// Round 7
// baseline (106.866 us; speedup 1.0000x reference)
//
#include <hip/hip_runtime.h>
#include <hip/hip_bf16.h>

typedef short short8 __attribute__((ext_vector_type(8)));
typedef float f32x4 __attribute__((ext_vector_type(4)));
typedef const void __attribute__((address_space(1))) as1_void;
typedef void __attribute__((address_space(3))) as3_void;

// hardware trig: input in revolutions (D = sin/cos(S0 * 2pi)), already in [0,1)
__device__ __forceinline__ float sin_rev(float r) {
  float o; asm("v_sin_f32 %0, %1" : "=v"(o) : "v"(r)); return o;
}
__device__ __forceinline__ float cos_rev(float r) {
  float o; asm("v_cos_f32 %0, %1" : "=v"(o) : "v"(r)); return o;
}

#define INV4096 0.000244140625f
#define INV16   0.0625f

// ---------------------------------------------------------------------------
// prep_kernel, grid = 3104 blocks x 256 thr, range-partitioned roles:
//   [0, 512)      F2 [512][4096] bf16: row=bid; rows 0..255 = cos m, 256..511 = -sin (m=row-255)
//   [512, 1024)   Gm [4096][512] bf16: 8 n-rows per block
//   [1024, 1056)  S[b][m] = (t_emb@dense_r + i t_emb@dense_i) * c_m/4096
//   [1056, 3104)  transpose x -> X2T bf16 [2048][4096] + Xr256p partials
// ---------------------------------------------------------------------------
__global__ __launch_bounds__(256) void prep_kernel(__hip_bfloat16* __restrict__ F2,
                                                   __hip_bfloat16* __restrict__ Gm,
                                                   const float* __restrict__ t_emb,
                                                   const float* __restrict__ dr,
                                                   const float* __restrict__ di,
                                                   float* __restrict__ Sr,
                                                   float* __restrict__ Si,
                                                   const float* __restrict__ x,
                                                   __hip_bfloat16* __restrict__ X2T,
                                                   float* __restrict__ Xr256p) {
  const int bid = blockIdx.x;
  const int tid = threadIdx.x;
  __shared__ float te[256];
  __shared__ float tile[64][65];
  __shared__ float red[4][64];

  if (bid < 512) {
    const int row = bid;
    const int m   = (row < 256) ? row : (row - 255);
    const bool is_cos = (row < 256);
#pragma unroll
    for (int it = 0; it < 2; ++it) {
      int n0 = it * 2048 + tid * 8;
      union { short8 v; unsigned short u[8]; } pk;
#pragma unroll
      for (int j = 0; j < 8; ++j) {
        int ph = (m * (n0 + j)) & 4095;
        float v = is_cos ?  cos_rev((float)ph * INV4096)
                         : -sin_rev((float)ph * INV4096);
        __hip_bfloat16 h = __float2bfloat16(v);
        pk.u[j] = *(unsigned short*)&h;
      }
      *(short8*)&F2[(size_t)row * 4096 + n0] = pk.v;
    }
  } else if (bid < 1024) {
    const int nb = (bid - 512) * 8;
#pragma unroll
    for (int it = 0; it < 2; ++it) {
      int e  = it * 2048 + tid * 8;     // 0..4095
      int n  = nb + (e >> 9);
      int k0 = e & 511;
      union { short8 v; unsigned short u[8]; } pk;
#pragma unroll
      for (int j = 0; j < 8; ++j) {
        int kk = k0 + j;
        int m  = (kk < 256) ? kk : (kk - 255);
        int ph = (m * n) & 4095;
        float v = (kk < 256) ?  cos_rev((float)ph * INV4096)
                             : -sin_rev((float)ph * INV4096);
        __hip_bfloat16 h = __float2bfloat16(v);
        pk.u[j] = *(unsigned short*)&h;
      }
      *(short8*)&Gm[(size_t)n * 512 + k0] = pk.v;
    }
  } else if (bid < 1056) {
    int b = bid - 1024;   // 0..31
    te[tid] = t_emb[b * 256 + tid];
    __syncthreads();
    for (int m = tid; m < 257; m += 256) {
      float ar = 0.f, ai = 0.f;
      for (int t = 0; t < 256; ++t) {
        float e = te[t];
        ar += e * dr[t * 257 + m];
        ai += e * di[t * 257 + m];
      }
      float c = (m == 0 ? 1.0f : 2.0f) * (1.0f / 4096.0f);
      Sr[b * 257 + m] = ar * c;
      Si[b * 257 + m] = ai * c;
    }
  } else {
    int idx = bid - 1056;         // 0..2047
    int nt = idx & 63;            // n-tile
    int b  = idx >> 6;            // batch
    int n0 = nt * 64;
#pragma unroll
    for (int it = 0; it < 4; ++it) {
      int c = it * 256 + tid;     // 0..1023 float4 chunks
      int r = c >> 4, i4 = (c & 15) * 4;
      float4 v = *(const float4*)&x[((size_t)b * 4096 + n0 + r) * 64 + i4];
      tile[r][i4 + 0] = v.x; tile[r][i4 + 1] = v.y;
      tile[r][i4 + 2] = v.z; tile[r][i4 + 3] = v.w;
    }
    __syncthreads();
    // coalesced transposed write: 8 lanes/row -> 128B contiguous chunks
#pragma unroll
    for (int it = 0; it < 2; ++it) {
      int c  = it * 256 + tid;    // 0..511
      int i  = c >> 3;            // 0..63
      int ch = c & 7;             // 0..7 (8-col chunk)
      union { short8 v; unsigned short u[8]; } pk;
#pragma unroll
      for (int j = 0; j < 8; ++j) {
        __hip_bfloat16 h = __float2bfloat16(tile[ch * 8 + j][i]);
        pk.u[j] = *(unsigned short*)&h;
      }
      *(short8*)&X2T[((size_t)b * 64 + i) * 4096 + n0 + ch * 8] = pk.v;
    }
    // Xr256 partial: sum_r cos(2pi r/16) * tile[r][i]   (r mod 16 periodic)
    {
      int i = tid & 63, g = tid >> 6;   // g: 16-row group
      float acc = 0.f;
#pragma unroll
      for (int j = 0; j < 16; ++j)
        acc += cos_rev((float)j * INV16) * tile[g * 16 + j][i];
      red[g][i] = acc;
    }
    __syncthreads();
    if (tid < 64) {
      Xr256p[((size_t)b * 64 + nt) * 64 + tid] =
          red[0][tid] + red[1][tid] + red[2][tid] + red[3][tid];
    }
  }
}

// ---------------------------------------------------------------------------
// MFMA GEMM core, single-buffer 2-barrier (m97 structure), templated on the
// B-tile width: NF = N-fragments per wave (4 -> BN=128, 2 -> BN=64).
// Wave grid 2x2: rows (wv>>1)*64, cols (wv&1)*(NF*16).
// T2 chunk-XOR swizzle via pre-swizzled global source (both-sides).
// ---------------------------------------------------------------------------
template <int NF>
__device__ __forceinline__ void stage_tileT(const __hip_bfloat16* __restrict__ A, int lda, int m0,
                                            const __hip_bfloat16* __restrict__ B, int ldb, int n0,
                                            int kt, __hip_bfloat16* As, __hip_bfloat16* Bs,
                                            int tid) {
#pragma unroll
  for (int j = 0; j < 4; ++j) {          // A tile: 128 rows x 64 k
    int c   = j * 256 + tid;             // 0..1023
    int row = c >> 3;
    int chg = (c & 7) ^ (row & 7);       // swizzled source chunk
    const __hip_bfloat16* ga = A + (size_t)(m0 + row) * lda + kt + chg * 8;
    __hip_bfloat16* la = As + (size_t)(j * 256 + (tid & 192)) * 8;
    __builtin_amdgcn_global_load_lds((as1_void*)ga, (as3_void*)la, 16, 0, 0);
  }
#pragma unroll
  for (int j = 0; j < NF; ++j) {         // B tile: NF*32 rows x 64 k
    int c   = j * 256 + tid;
    int row = c >> 3;
    int chg = (c & 7) ^ (row & 7);
    const __hip_bfloat16* gb = B + (size_t)(n0 + row) * ldb + kt + chg * 8;
    __hip_bfloat16* lb = Bs + (size_t)(j * 256 + (tid & 192)) * 8;
    __builtin_amdgcn_global_load_lds((as1_void*)gb, (as3_void*)lb, 16, 0, 0);
  }
}

template <int NF>
__device__ __forceinline__ void compute_stepT(const __hip_bfloat16* As, const __hip_bfloat16* Bs,
                                              int wr, int wc, int fr, int fq,
                                              f32x4 acc[4][NF]) {
#pragma unroll
  for (int kk = 0; kk < 2; ++kk) {
    short8 av[4], bv[NF];
#pragma unroll
    for (int m = 0; m < 4; ++m) {
      int row  = wr + m * 16 + fr;
      int slot = (fq + kk * 4) ^ (row & 7);
      av[m] = *(const short8*)(As + row * 64 + slot * 8);
    }
#pragma unroll
    for (int n = 0; n < NF; ++n) {
      int row  = wc + n * 16 + fr;
      int slot = (fq + kk * 4) ^ (row & 7);
      bv[n] = *(const short8*)(Bs + row * 64 + slot * 8);
    }
#pragma unroll
    for (int m = 0; m < 4; ++m)
#pragma unroll
      for (int n = 0; n < NF; ++n)
        acc[m][n] = __builtin_amdgcn_mfma_f32_16x16x32_bf16(av[m], bv[n], acc[m][n], 0, 0, 0);
  }
}

template <int NF>
__device__ __forceinline__ void gemm_coreT(const __hip_bfloat16* __restrict__ A, int lda, int m0,
                                           const __hip_bfloat16* __restrict__ B, int ldb, int n0,
                                           int k0, int ksteps,
                                           __hip_bfloat16* As, __hip_bfloat16* Bs,
                                           f32x4 acc[4][NF]) {
  const int tid  = threadIdx.x;
  const int lane = tid & 63;
  const int wv   = tid >> 6;
  const int wr   = (wv >> 1) * 64;
  const int wc   = (wv & 1) * (NF * 16);
  const int fr   = lane & 15;
  const int fq   = lane >> 4;

  for (int ks = 0; ks < ksteps; ++ks) {
    stage_tileT<NF>(A, lda, m0, B, ldb, n0, k0 + ks * 64, As, Bs, tid);
    __syncthreads();
    compute_stepT<NF>(As, Bs, wr, wc, fr, fq, acc);
    __syncthreads();
  }
}

// GEMM1: C1[z][row][bi] (bf16 split-K partials) = F2 @ X2T^T   (512 rows, all live)
__global__ __launch_bounds__(256) void gemm1_kernel(const __hip_bfloat16* __restrict__ F2,
                                                    const __hip_bfloat16* __restrict__ X2T,
                                                    __hip_bfloat16* __restrict__ C1, int kchunk) {
  __shared__ __hip_bfloat16 As[128 * 64];
  __shared__ __hip_bfloat16 Bs[128 * 64];
  int n0 = blockIdx.x * 128;
  int m0 = blockIdx.y * 128;
  int k0 = blockIdx.z * kchunk;
  f32x4 acc[4][4];
#pragma unroll
  for (int m = 0; m < 4; ++m)
#pragma unroll
    for (int n = 0; n < 4; ++n)
#pragma unroll
      for (int r = 0; r < 4; ++r) acc[m][n][r] = 0.f;

  gemm_coreT<4>(F2, 4096, m0, X2T, 4096, n0, k0, kchunk >> 6, As, Bs, acc);

  const int lane = threadIdx.x & 63;
  const int wv   = threadIdx.x >> 6;
  const int wr   = (wv >> 1) * 64, wc = (wv & 1) * 64;
  const int fr   = lane & 15, fq = lane >> 4;
  __hip_bfloat16* P = C1 + (size_t)blockIdx.z * (512 * 2048);
#pragma unroll
  for (int m = 0; m < 4; ++m)
#pragma unroll
    for (int n = 0; n < 4; ++n)
#pragma unroll
      for (int j = 0; j < 4; ++j) {
        int row = m0 + wr + m * 16 + fq * 4 + j;
        int col = n0 + wc + n * 16 + fr;
        P[(size_t)row * 2048 + col] = __float2bfloat16(acc[m][n][j]);
      }
}

// ---------------------------------------------------------------------------
// Mode mix (fused split-K reduce, direct transposed output)
// ---------------------------------------------------------------------------
__global__ __launch_bounds__(256) void mix_kernel(const __hip_bfloat16* __restrict__ C1,
                                                  const float* __restrict__ Xr256p,
                                                  const float* __restrict__ Wr,
                                                  const float* __restrict__ Wi,
                                                  const float* __restrict__ Sr,
                                                  const float* __restrict__ Si,
                                                  __hip_bfloat16* __restrict__ Y2T,
                                                  __hip_bfloat16* __restrict__ Yx,
                                                  int splitk) {
  const int k = blockIdx.x;   // 0..256
  const int q = blockIdx.y;   // 0..3 (batches q*8 .. q*8+7)
  const int tid = threadIdx.x;
  __shared__ float wlr[4096];
  __shared__ float wli[4096];
  __shared__ float xs[1024];   // [0..511]=real, [512..1023]=imag; col = bl*64+i

  const float* wrg = Wr + (size_t)k * 4096;
  const float* wig = Wi + (size_t)k * 4096;
  for (int c = tid; c < 1024; c += 256) {
    *(float4*)&wlr[c * 4] = *(const float4*)&wrg[c * 4];
    *(float4*)&wli[c * 4] = *(const float4*)&wig[c * 4];
  }
  const size_t PST = 512ull * 2048;
  for (int idx = tid; idx < 1024; idx += 256) {
    int part = idx >> 9;
    int c    = idx & 511;
    float s = 0.f;
    if (part == 0) {
      if (k < 256) {
        const __hip_bfloat16* src = C1 + (size_t)k * 2048 + q * 512 + c;
        for (int z = 0; z < splitk; ++z) s += __bfloat162float(src[(size_t)z * PST]);
      } else {
        int bi = q * 512 + c;
        const float* sp = Xr256p + (size_t)(bi >> 6) * 4096 + (bi & 63);
#pragma unroll 8
        for (int nt = 0; nt < 64; ++nt) s += sp[nt * 64];
      }
    } else if (k > 0) {
      const __hip_bfloat16* src = C1 + (size_t)(255 + k) * 2048 + q * 512 + c;
      for (int z = 0; z < splitk; ++z) s += __bfloat162float(src[(size_t)z * PST]);
    }
    xs[idx] = s;
  }
  __syncthreads();

  const int o  = tid & 63;
  const int jj = tid >> 6;          // 0..3
  const int bl0 = jj * 2, bl1 = jj * 2 + 1;
  float pr0 = 0.f, pi0 = 0.f, pr1 = 0.f, pi1 = 0.f;
#pragma unroll 8
  for (int i = 0; i < 64; ++i) {
    float wrv = wlr[i * 64 + o];
    float wiv = wli[i * 64 + o];
    float xr0 = xs[bl0 * 64 + i], xi0 = xs[512 + bl0 * 64 + i];
    float xr1 = xs[bl1 * 64 + i], xi1 = xs[512 + bl1 * 64 + i];
    pr0 += xr0 * wrv - xi0 * wiv;
    pi0 += xr0 * wiv + xi0 * wrv;
    pr1 += xr1 * wrv - xi1 * wiv;
    pi1 += xr1 * wiv + xi1 * wrv;
  }
  int b0 = q * 8 + bl0, b1 = q * 8 + bl1;
  float sr0 = Sr[b0 * 257 + k], si0 = Si[b0 * 257 + k];
  float sr1 = Sr[b1 * 257 + k], si1 = Si[b1 * 257 + k];
  int bo0 = b0 * 64 + o, bo1 = b1 * 64 + o;
  __hip_bfloat16 yr0 = __float2bfloat16(pr0 * sr0 - pi0 * si0);
  __hip_bfloat16 yi0 = __float2bfloat16(pr0 * si0 + pi0 * sr0);
  __hip_bfloat16 yr1 = __float2bfloat16(pr1 * sr1 - pi1 * si1);
  __hip_bfloat16 yi1 = __float2bfloat16(pr1 * si1 + pi1 * sr1);
  if (k < 256) {
    Y2T[(size_t)bo0 * 512 + k] = yr0;
    Y2T[(size_t)bo1 * 512 + k] = yr1;
  } else {
    Yx[bo0] = yr0;
    Yx[bo1] = yr1;
  }
  if (k >= 1) {
    Y2T[(size_t)bo0 * 512 + 255 + k] = yi0;
    Y2T[(size_t)bo1 * 512 + 255 + k] = yi1;
  }
}

// GEMM2: out[b][n][o] = Gm[n][:] . Y2T[bo][:]  + cos(2 pi n/16) * Yx[bo]
// tile 128(n) x 64(bo), NF=2, 1024 blocks
__global__ __launch_bounds__(256) void gemm2_kernel(const __hip_bfloat16* __restrict__ Gm,
                                                    const __hip_bfloat16* __restrict__ Y2T,
                                                    const __hip_bfloat16* __restrict__ Yx,
                                                    float* __restrict__ out) {
  __shared__ __hip_bfloat16 As[128 * 64];
  __shared__ __hip_bfloat16 Bs[64 * 64];
  int n0 = blockIdx.x * 64;    // bo
  int m0 = blockIdx.y * 128;   // n (time)
  f32x4 acc[4][2];
#pragma unroll
  for (int m = 0; m < 4; ++m)
#pragma unroll
    for (int n = 0; n < 2; ++n)
#pragma unroll
      for (int r = 0; r < 4; ++r) acc[m][n][r] = 0.f;

  gemm_coreT<2>(Gm, 512, m0, Y2T, 512, n0, 0, 8, As, Bs, acc);

  const int lane = threadIdx.x & 63;
  const int wv   = threadIdx.x >> 6;
  const int wr   = (wv >> 1) * 64, wc = (wv & 1) * 32;
  const int fr   = lane & 15, fq = lane >> 4;
  float yx[2];
#pragma unroll
  for (int n = 0; n < 2; ++n)
    yx[n] = __bfloat162float(Yx[n0 + wc + n * 16 + fr]);
#pragma unroll
  for (int m = 0; m < 4; ++m)
#pragma unroll
    for (int j = 0; j < 4; ++j) {
      int row = m0 + wr + m * 16 + fq * 4 + j;   // n index
      float g = cos_rev((float)(row & 15) * INV16);
#pragma unroll
      for (int n = 0; n < 2; ++n) {
        int col = n0 + wc + n * 16 + fr;         // bo index
        int b = col >> 6, o = col & 63;
        out[((size_t)b * 4096 + row) * 64 + o] = acc[m][n][j] + g * yx[n];
      }
    }
}

// ---------------------------------------------------------------------------
extern "C" void kernel_launch(void* const* d_in, const int* in_sizes, int n_in,
                              void* d_out, int out_size, void* d_ws, size_t ws_size,
                              hipStream_t stream) {
  const float* x  = (const float*)d_in[0];   // (32,4096,64)
  const float* te = (const float*)d_in[1];   // (32,256)
  const float* wr = (const float*)d_in[2];   // (257,64,64)
  const float* wi = (const float*)d_in[3];
  const float* dr = (const float*)d_in[4];   // (256,257)
  const float* di = (const float*)d_in[5];
  float* out = (float*)d_out;

  char* p = (char*)d_ws;
  auto alloc = [&](size_t bytes) -> char* {
    char* r = p;
    p += (bytes + 255) & ~(size_t)255;
    return r;
  };
  __hip_bfloat16* F2  = (__hip_bfloat16*)alloc(512ull * 4096 * 2);
  __hip_bfloat16* Gm  = (__hip_bfloat16*)alloc(4096ull * 512 * 2);
  __hip_bfloat16* X2T = (__hip_bfloat16*)alloc(2048ull * 4096 * 2);
  float* Xr256p = (float*)alloc(32ull * 64 * 64 * 4);   // [b][nt][i]
  float* Sr = (float*)alloc(32 * 257 * 4);
  float* Si = (float*)alloc(32 * 257 * 4);
  __hip_bfloat16* Y2T = (__hip_bfloat16*)alloc(2048ull * 512 * 2);
  __hip_bfloat16* Yx  = (__hip_bfloat16*)alloc(2048 * 2);
  size_t fixed = (size_t)(p - (char*)d_ws);

  int splitk = 1;
  if (ws_size >= fixed + 16ull * 512 * 2048 * 2)      splitk = 16;
  else if (ws_size >= fixed + 8ull * 512 * 2048 * 2)  splitk = 8;
  else if (ws_size >= fixed + 4ull * 512 * 2048 * 2)  splitk = 4;
  else if (ws_size >= fixed + 2ull * 512 * 2048 * 2)  splitk = 2;
  __hip_bfloat16* C1 = (__hip_bfloat16*)alloc((size_t)splitk * 512 * 2048 * 2);
  int kchunk = 4096 / splitk;

  prep_kernel<<<3104, 256, 0, stream>>>(F2, Gm, te, dr, di, Sr, Si, x, X2T, Xr256p);
  gemm1_kernel<<<dim3(16, 4, splitk), 256, 0, stream>>>(F2, X2T, C1, kchunk);
  mix_kernel<<<dim3(257, 4), 256, 0, stream>>>(C1, Xr256p, wr, wi, Sr, Si, Y2T, Yx, splitk);
  gemm2_kernel<<<dim3(32, 32), 256, 0, stream>>>(Gm, Y2T, Yx, out);
}

// Round 8
// 89.716 us; speedup vs baseline: 1.1912x; 1.1912x over previous
//
#include <hip/hip_runtime.h>
#include <hip/hip_bf16.h>

typedef short short8 __attribute__((ext_vector_type(8)));
typedef float f32x4 __attribute__((ext_vector_type(4)));
typedef const void __attribute__((address_space(1))) as1_void;
typedef void __attribute__((address_space(3))) as3_void;

// hardware trig: input in revolutions (D = sin/cos(S0 * 2pi)), already in [0,1)
__device__ __forceinline__ float sin_rev(float r) {
  float o; asm("v_sin_f32 %0, %1" : "=v"(o) : "v"(r)); return o;
}
__device__ __forceinline__ float cos_rev(float r) {
  float o; asm("v_cos_f32 %0, %1" : "=v"(o) : "v"(r)); return o;
}

#define INV4096 0.000244140625f
#define INV16   0.0625f

// ---------------------------------------------------------------------------
// prep_kernel, grid = 4132 blocks x 256 thr, range-partitioned roles:
//   [0, 512)      F2 [512][4096] bf16: row=bid; rows 0..255 = cos m, 256..511 = -sin (m=row-255)
//   [512, 1024)   Gm [4096][512] bf16: 8 n-rows per block
//   [1024, 1056)  S[b][m] = (t_emb@dense_r + i t_emb@dense_i) * c_m/4096
//   [1056, 3104)  transpose x -> X2T bf16 [2048][4096] + Xr256p partials
//   [3104, 4132)  Wb[k][2][4096] bf16 <- {Wr,Wi}[k] fp32   (1028 blocks, 2048 elems each)
// ---------------------------------------------------------------------------
__global__ __launch_bounds__(256) void prep_kernel(__hip_bfloat16* __restrict__ F2,
                                                   __hip_bfloat16* __restrict__ Gm,
                                                   const float* __restrict__ t_emb,
                                                   const float* __restrict__ dr,
                                                   const float* __restrict__ di,
                                                   float* __restrict__ Sr,
                                                   float* __restrict__ Si,
                                                   const float* __restrict__ x,
                                                   __hip_bfloat16* __restrict__ X2T,
                                                   float* __restrict__ Xr256p,
                                                   const float* __restrict__ Wr,
                                                   const float* __restrict__ Wi,
                                                   __hip_bfloat16* __restrict__ Wb) {
  const int bid = blockIdx.x;
  const int tid = threadIdx.x;
  __shared__ float te[256];
  __shared__ float tile[64][65];
  __shared__ float red[4][64];

  if (bid < 512) {
    const int row = bid;
    const int m   = (row < 256) ? row : (row - 255);
    const bool is_cos = (row < 256);
#pragma unroll
    for (int it = 0; it < 2; ++it) {
      int n0 = it * 2048 + tid * 8;
      union { short8 v; unsigned short u[8]; } pk;
#pragma unroll
      for (int j = 0; j < 8; ++j) {
        int ph = (m * (n0 + j)) & 4095;
        float v = is_cos ?  cos_rev((float)ph * INV4096)
                         : -sin_rev((float)ph * INV4096);
        __hip_bfloat16 h = __float2bfloat16(v);
        pk.u[j] = *(unsigned short*)&h;
      }
      *(short8*)&F2[(size_t)row * 4096 + n0] = pk.v;
    }
  } else if (bid < 1024) {
    const int nb = (bid - 512) * 8;
#pragma unroll
    for (int it = 0; it < 2; ++it) {
      int e  = it * 2048 + tid * 8;     // 0..4095
      int n  = nb + (e >> 9);
      int k0 = e & 511;
      union { short8 v; unsigned short u[8]; } pk;
#pragma unroll
      for (int j = 0; j < 8; ++j) {
        int kk = k0 + j;
        int m  = (kk < 256) ? kk : (kk - 255);
        int ph = (m * n) & 4095;
        float v = (kk < 256) ?  cos_rev((float)ph * INV4096)
                             : -sin_rev((float)ph * INV4096);
        __hip_bfloat16 h = __float2bfloat16(v);
        pk.u[j] = *(unsigned short*)&h;
      }
      *(short8*)&Gm[(size_t)n * 512 + k0] = pk.v;
    }
  } else if (bid < 1056) {
    int b = bid - 1024;   // 0..31
    te[tid] = t_emb[b * 256 + tid];
    __syncthreads();
    for (int m = tid; m < 257; m += 256) {
      float ar = 0.f, ai = 0.f;
      for (int t = 0; t < 256; ++t) {
        float e = te[t];
        ar += e * dr[t * 257 + m];
        ai += e * di[t * 257 + m];
      }
      float c = (m == 0 ? 1.0f : 2.0f) * (1.0f / 4096.0f);
      Sr[b * 257 + m] = ar * c;
      Si[b * 257 + m] = ai * c;
    }
  } else if (bid < 3104) {
    int idx = bid - 1056;         // 0..2047
    int nt = idx & 63;            // n-tile
    int b  = idx >> 6;            // batch
    int n0 = nt * 64;
#pragma unroll
    for (int it = 0; it < 4; ++it) {
      int c = it * 256 + tid;     // 0..1023 float4 chunks
      int r = c >> 4, i4 = (c & 15) * 4;
      float4 v = *(const float4*)&x[((size_t)b * 4096 + n0 + r) * 64 + i4];
      tile[r][i4 + 0] = v.x; tile[r][i4 + 1] = v.y;
      tile[r][i4 + 2] = v.z; tile[r][i4 + 3] = v.w;
    }
    __syncthreads();
    // coalesced transposed write: 8 lanes/row -> 128B contiguous chunks
#pragma unroll
    for (int it = 0; it < 2; ++it) {
      int c  = it * 256 + tid;    // 0..511
      int i  = c >> 3;            // 0..63
      int ch = c & 7;             // 0..7 (8-col chunk)
      union { short8 v; unsigned short u[8]; } pk;
#pragma unroll
      for (int j = 0; j < 8; ++j) {
        __hip_bfloat16 h = __float2bfloat16(tile[ch * 8 + j][i]);
        pk.u[j] = *(unsigned short*)&h;
      }
      *(short8*)&X2T[((size_t)b * 64 + i) * 4096 + n0 + ch * 8] = pk.v;
    }
    // Xr256 partial: sum_r cos(2pi r/16) * tile[r][i]   (r mod 16 periodic)
    {
      int i = tid & 63, g = tid >> 6;   // g: 16-row group
      float acc = 0.f;
#pragma unroll
      for (int j = 0; j < 16; ++j)
        acc += cos_rev((float)j * INV16) * tile[g * 16 + j][i];
      red[g][i] = acc;
    }
    __syncthreads();
    if (tid < 64) {
      Xr256p[((size_t)b * 64 + nt) * 64 + tid] =
          red[0][tid] + red[1][tid] + red[2][tid] + red[3][tid];
    }
  } else {
    // W fp32 -> bf16 repack: Wb[k][0][*]=Wr[k], Wb[k][1][*]=Wi[k]
    int idx  = bid - 3104;        // 0..1027
    int k    = idx >> 2;
    int quad = idx & 3;           // 0,1 -> real halves; 2,3 -> imag halves
    const float* src = (quad < 2) ? (Wr + (size_t)k * 4096 + quad * 2048)
                                  : (Wi + (size_t)k * 4096 + (quad - 2) * 2048);
    __hip_bfloat16* dst = Wb + (size_t)k * 8192 + (quad < 2 ? quad * 2048 : 4096 + (quad - 2) * 2048);
    int e = tid * 8;
    float4 v0 = *(const float4*)&src[e];
    float4 v1 = *(const float4*)&src[e + 4];
    union { short8 v; unsigned short u[8]; } pk;
    float vv[8] = {v0.x, v0.y, v0.z, v0.w, v1.x, v1.y, v1.z, v1.w};
#pragma unroll
    for (int j = 0; j < 8; ++j) {
      __hip_bfloat16 h = __float2bfloat16(vv[j]);
      pk.u[j] = *(unsigned short*)&h;
    }
    *(short8*)&dst[e] = pk.v;
  }
}

// ---------------------------------------------------------------------------
// MFMA GEMM core, single-buffer 2-barrier (m97 structure), templated on the
// B-tile width: NF = N-fragments per wave (4 -> BN=128, 2 -> BN=64).
// T2 chunk-XOR swizzle via pre-swizzled global source (both-sides).
// ---------------------------------------------------------------------------
template <int NF>
__device__ __forceinline__ void stage_tileT(const __hip_bfloat16* __restrict__ A, int lda, int m0,
                                            const __hip_bfloat16* __restrict__ B, int ldb, int n0,
                                            int kt, __hip_bfloat16* As, __hip_bfloat16* Bs,
                                            int tid) {
#pragma unroll
  for (int j = 0; j < 4; ++j) {          // A tile: 128 rows x 64 k
    int c   = j * 256 + tid;             // 0..1023
    int row = c >> 3;
    int chg = (c & 7) ^ (row & 7);       // swizzled source chunk
    const __hip_bfloat16* ga = A + (size_t)(m0 + row) * lda + kt + chg * 8;
    __hip_bfloat16* la = As + (size_t)(j * 256 + (tid & 192)) * 8;
    __builtin_amdgcn_global_load_lds((as1_void*)ga, (as3_void*)la, 16, 0, 0);
  }
#pragma unroll
  for (int j = 0; j < NF; ++j) {         // B tile: NF*32 rows x 64 k
    int c   = j * 256 + tid;
    int row = c >> 3;
    int chg = (c & 7) ^ (row & 7);
    const __hip_bfloat16* gb = B + (size_t)(n0 + row) * ldb + kt + chg * 8;
    __hip_bfloat16* lb = Bs + (size_t)(j * 256 + (tid & 192)) * 8;
    __builtin_amdgcn_global_load_lds((as1_void*)gb, (as3_void*)lb, 16, 0, 0);
  }
}

template <int NF>
__device__ __forceinline__ void compute_stepT(const __hip_bfloat16* As, const __hip_bfloat16* Bs,
                                              int wr, int wc, int fr, int fq,
                                              f32x4 acc[4][NF]) {
#pragma unroll
  for (int kk = 0; kk < 2; ++kk) {
    short8 av[4], bv[NF];
#pragma unroll
    for (int m = 0; m < 4; ++m) {
      int row  = wr + m * 16 + fr;
      int slot = (fq + kk * 4) ^ (row & 7);
      av[m] = *(const short8*)(As + row * 64 + slot * 8);
    }
#pragma unroll
    for (int n = 0; n < NF; ++n) {
      int row  = wc + n * 16 + fr;
      int slot = (fq + kk * 4) ^ (row & 7);
      bv[n] = *(const short8*)(Bs + row * 64 + slot * 8);
    }
#pragma unroll
    for (int m = 0; m < 4; ++m)
#pragma unroll
      for (int n = 0; n < NF; ++n)
        acc[m][n] = __builtin_amdgcn_mfma_f32_16x16x32_bf16(av[m], bv[n], acc[m][n], 0, 0, 0);
  }
}

template <int NF>
__device__ __forceinline__ void gemm_coreT(const __hip_bfloat16* __restrict__ A, int lda, int m0,
                                           const __hip_bfloat16* __restrict__ B, int ldb, int n0,
                                           int k0, int ksteps,
                                           __hip_bfloat16* As, __hip_bfloat16* Bs,
                                           f32x4 acc[4][NF]) {
  const int tid  = threadIdx.x;
  const int lane = tid & 63;
  const int wv   = tid >> 6;
  const int wr   = (wv >> 1) * 64;
  const int wc   = (wv & 1) * (NF * 16);
  const int fr   = lane & 15;
  const int fq   = lane >> 4;

  for (int ks = 0; ks < ksteps; ++ks) {
    stage_tileT<NF>(A, lda, m0, B, ldb, n0, k0 + ks * 64, As, Bs, tid);
    __syncthreads();
    compute_stepT<NF>(As, Bs, wr, wc, fr, fq, acc);
    __syncthreads();
  }
}

// GEMM1: C1[z][row][bi] (bf16 split-K partials) = F2 @ X2T^T   (512 rows, all live)
__global__ __launch_bounds__(256) void gemm1_kernel(const __hip_bfloat16* __restrict__ F2,
                                                    const __hip_bfloat16* __restrict__ X2T,
                                                    __hip_bfloat16* __restrict__ C1, int kchunk) {
  __shared__ __hip_bfloat16 As[128 * 64];
  __shared__ __hip_bfloat16 Bs[128 * 64];
  int n0 = blockIdx.x * 128;
  int m0 = blockIdx.y * 128;
  int k0 = blockIdx.z * kchunk;
  f32x4 acc[4][4];
#pragma unroll
  for (int m = 0; m < 4; ++m)
#pragma unroll
    for (int n = 0; n < 4; ++n)
#pragma unroll
      for (int r = 0; r < 4; ++r) acc[m][n][r] = 0.f;

  gemm_coreT<4>(F2, 4096, m0, X2T, 4096, n0, k0, kchunk >> 6, As, Bs, acc);

  const int lane = threadIdx.x & 63;
  const int wv   = threadIdx.x >> 6;
  const int wr   = (wv >> 1) * 64, wc = (wv & 1) * 64;
  const int fr   = lane & 15, fq = lane >> 4;
  __hip_bfloat16* P = C1 + (size_t)blockIdx.z * (512 * 2048);
#pragma unroll
  for (int m = 0; m < 4; ++m)
#pragma unroll
    for (int n = 0; n < 4; ++n)
#pragma unroll
      for (int j = 0; j < 4; ++j) {
        int row = m0 + wr + m * 16 + fq * 4 + j;
        int col = n0 + wc + n * 16 + fr;
        P[(size_t)row * 2048 + col] = __float2bfloat16(acc[m][n][j]);
      }
}

// ---------------------------------------------------------------------------
// Mode mix (fused split-K reduce, vectorized short8 C1 reads, bf16 weights)
// ---------------------------------------------------------------------------
__global__ __launch_bounds__(256) void mix_kernel(const __hip_bfloat16* __restrict__ C1,
                                                  const float* __restrict__ Xr256p,
                                                  const __hip_bfloat16* __restrict__ Wb,
                                                  const float* __restrict__ Sr,
                                                  const float* __restrict__ Si,
                                                  __hip_bfloat16* __restrict__ Y2T,
                                                  __hip_bfloat16* __restrict__ Yx,
                                                  int splitk) {
  const int k = blockIdx.x;   // 0..256
  const int q = blockIdx.y;   // 0..3 (batches q*8 .. q*8+7)
  const int tid = threadIdx.x;
  __shared__ float wlr[4096];
  __shared__ float wli[4096];
  __shared__ float xs2[2][1024];
  __shared__ float xs[1024];   // [0..511]=real, [512..1023]=imag; col = bl*64+i

  // stage weights for mode k: 16 KB bf16 -> fp32 LDS
  const __hip_bfloat16* wbg = Wb + (size_t)k * 8192;   // [r 4096][i 4096]
  for (int c = tid; c < 1024; c += 256) {
    short8 v = *(const short8*)(wbg + c * 8);
    float* dst = (c < 512) ? &wlr[c * 8] : &wli[(c - 512) * 8];
#pragma unroll
    for (int j = 0; j < 8; ++j) {
      unsigned short u = (unsigned short)v[j];
      dst[j] = __bfloat162float(*(__hip_bfloat16*)&u);
    }
  }

  const size_t PST = 512ull * 2048;
  if (k < 256) {
    // vectorized split-K reduce: zg halves the z range, 16B loads
    const int zg   = tid >> 7;          // 0..1
    const int part = (tid >> 6) & 1;    // 0=real,1=imag
    const int ln   = tid & 63;
    const int row  = (part == 0) ? k : 255 + k;
    float f[8] = {0.f, 0.f, 0.f, 0.f, 0.f, 0.f, 0.f, 0.f};
    if (part == 0 || k > 0) {
      const __hip_bfloat16* src = C1 + (size_t)row * 2048 + q * 512 + ln * 8;
      const int zh = splitk >> 1;
      for (int z = zg * zh; z < zg * zh + zh; ++z) {
        short8 v = *(const short8*)(src + (size_t)z * PST);
#pragma unroll
        for (int j = 0; j < 8; ++j) {
          unsigned short u = (unsigned short)v[j];
          f[j] += __bfloat162float(*(__hip_bfloat16*)&u);
        }
      }
    }
#pragma unroll
    for (int j = 0; j < 8; ++j) xs2[zg][part * 512 + ln * 8 + j] = f[j];
    __syncthreads();
    for (int e = tid; e < 1024; e += 256) xs[e] = xs2[0][e] + xs2[1][e];
  } else {
    // k == 256: real from Xr256p partials, imag from C1 row 511
    for (int idx = tid; idx < 1024; idx += 256) {
      int part = idx >> 9;
      int c    = idx & 511;
      float s = 0.f;
      if (part == 0) {
        int bi = q * 512 + c;
        const float* sp = Xr256p + (size_t)(bi >> 6) * 4096 + (bi & 63);
#pragma unroll 8
        for (int nt = 0; nt < 64; ++nt) s += sp[nt * 64];
      } else {
        const __hip_bfloat16* src = C1 + (size_t)511 * 2048 + q * 512 + c;
        for (int z = 0; z < splitk; ++z) s += __bfloat162float(src[(size_t)z * PST]);
      }
      xs[idx] = s;
    }
    __syncthreads();   // match barrier count of the other branch
  }
  __syncthreads();

  const int o  = tid & 63;
  const int jj = tid >> 6;          // 0..3
  const int bl0 = jj * 2, bl1 = jj * 2 + 1;
  float pr0 = 0.f, pi0 = 0.f, pr1 = 0.f, pi1 = 0.f;
#pragma unroll 8
  for (int i = 0; i < 64; ++i) {
    float wrv = wlr[i * 64 + o];
    float wiv = wli[i * 64 + o];
    float xr0 = xs[bl0 * 64 + i], xi0 = xs[512 + bl0 * 64 + i];
    float xr1 = xs[bl1 * 64 + i], xi1 = xs[512 + bl1 * 64 + i];
    pr0 += xr0 * wrv - xi0 * wiv;
    pi0 += xr0 * wiv + xi0 * wrv;
    pr1 += xr1 * wrv - xi1 * wiv;
    pi1 += xr1 * wiv + xi1 * wrv;
  }
  int b0 = q * 8 + bl0, b1 = q * 8 + bl1;
  float sr0 = Sr[b0 * 257 + k], si0 = Si[b0 * 257 + k];
  float sr1 = Sr[b1 * 257 + k], si1 = Si[b1 * 257 + k];
  int bo0 = b0 * 64 + o, bo1 = b1 * 64 + o;
  __hip_bfloat16 yr0 = __float2bfloat16(pr0 * sr0 - pi0 * si0);
  __hip_bfloat16 yi0 = __float2bfloat16(pr0 * si0 + pi0 * sr0);
  __hip_bfloat16 yr1 = __float2bfloat16(pr1 * sr1 - pi1 * si1);
  __hip_bfloat16 yi1 = __float2bfloat16(pr1 * si1 + pi1 * sr1);
  if (k < 256) {
    Y2T[(size_t)bo0 * 512 + k] = yr0;
    Y2T[(size_t)bo1 * 512 + k] = yr1;
  } else {
    Yx[bo0] = yr0;
    Yx[bo1] = yr1;
  }
  if (k >= 1) {
    Y2T[(size_t)bo0 * 512 + 255 + k] = yi0;
    Y2T[(size_t)bo1 * 512 + 255 + k] = yi1;
  }
}

// GEMM2: out[b][n][o] = Gm[n][:] . Y2T[bo][:]  + cos(2 pi n/16) * Yx[bo]
// tile 128(n) x 64(bo), NF=2, 1024 blocks
__global__ __launch_bounds__(256) void gemm2_kernel(const __hip_bfloat16* __restrict__ Gm,
                                                    const __hip_bfloat16* __restrict__ Y2T,
                                                    const __hip_bfloat16* __restrict__ Yx,
                                                    float* __restrict__ out) {
  __shared__ __hip_bfloat16 As[128 * 64];
  __shared__ __hip_bfloat16 Bs[64 * 64];
  int n0 = blockIdx.x * 64;    // bo
  int m0 = blockIdx.y * 128;   // n (time)
  f32x4 acc[4][2];
#pragma unroll
  for (int m = 0; m < 4; ++m)
#pragma unroll
    for (int n = 0; n < 2; ++n)
#pragma unroll
      for (int r = 0; r < 4; ++r) acc[m][n][r] = 0.f;

  gemm_coreT<2>(Gm, 512, m0, Y2T, 512, n0, 0, 8, As, Bs, acc);

  const int lane = threadIdx.x & 63;
  const int wv   = threadIdx.x >> 6;
  const int wr   = (wv >> 1) * 64, wc = (wv & 1) * 32;
  const int fr   = lane & 15, fq = lane >> 4;
  float yx[2];
#pragma unroll
  for (int n = 0; n < 2; ++n)
    yx[n] = __bfloat162float(Yx[n0 + wc + n * 16 + fr]);
#pragma unroll
  for (int m = 0; m < 4; ++m)
#pragma unroll
    for (int j = 0; j < 4; ++j) {
      int row = m0 + wr + m * 16 + fq * 4 + j;   // n index
      float g = cos_rev((float)(row & 15) * INV16);
#pragma unroll
      for (int n = 0; n < 2; ++n) {
        int col = n0 + wc + n * 16 + fr;         // bo index
        int b = col >> 6, o = col & 63;
        out[((size_t)b * 4096 + row) * 64 + o] = acc[m][n][j] + g * yx[n];
      }
    }
}

// ---------------------------------------------------------------------------
extern "C" void kernel_launch(void* const* d_in, const int* in_sizes, int n_in,
                              void* d_out, int out_size, void* d_ws, size_t ws_size,
                              hipStream_t stream) {
  const float* x  = (const float*)d_in[0];   // (32,4096,64)
  const float* te = (const float*)d_in[1];   // (32,256)
  const float* wr = (const float*)d_in[2];   // (257,64,64)
  const float* wi = (const float*)d_in[3];
  const float* dr = (const float*)d_in[4];   // (256,257)
  const float* di = (const float*)d_in[5];
  float* out = (float*)d_out;

  char* p = (char*)d_ws;
  auto alloc = [&](size_t bytes) -> char* {
    char* r = p;
    p += (bytes + 255) & ~(size_t)255;
    return r;
  };
  __hip_bfloat16* F2  = (__hip_bfloat16*)alloc(512ull * 4096 * 2);
  __hip_bfloat16* Gm  = (__hip_bfloat16*)alloc(4096ull * 512 * 2);
  __hip_bfloat16* X2T = (__hip_bfloat16*)alloc(2048ull * 4096 * 2);
  float* Xr256p = (float*)alloc(32ull * 64 * 64 * 4);   // [b][nt][i]
  float* Sr = (float*)alloc(32 * 257 * 4);
  float* Si = (float*)alloc(32 * 257 * 4);
  __hip_bfloat16* Y2T = (__hip_bfloat16*)alloc(2048ull * 512 * 2);
  __hip_bfloat16* Yx  = (__hip_bfloat16*)alloc(2048 * 2);
  __hip_bfloat16* Wb  = (__hip_bfloat16*)alloc(257ull * 8192 * 2);
  size_t fixed = (size_t)(p - (char*)d_ws);

  int splitk = 2;
  if (ws_size >= fixed + 8ull * 512 * 2048 * 2)      splitk = 8;
  else if (ws_size >= fixed + 4ull * 512 * 2048 * 2) splitk = 4;
  __hip_bfloat16* C1 = (__hip_bfloat16*)alloc((size_t)splitk * 512 * 2048 * 2);
  int kchunk = 4096 / splitk;

  prep_kernel<<<4132, 256, 0, stream>>>(F2, Gm, te, dr, di, Sr, Si, x, X2T, Xr256p, wr, wi, Wb);
  gemm1_kernel<<<dim3(16, 4, splitk), 256, 0, stream>>>(F2, X2T, C1, kchunk);
  mix_kernel<<<dim3(257, 4), 256, 0, stream>>>(C1, Xr256p, Wb, Sr, Si, Y2T, Yx, splitk);
  gemm2_kernel<<<dim3(32, 32), 256, 0, stream>>>(Gm, Y2T, Yx, out);
}

// Round 9
// 88.866 us; speedup vs baseline: 1.2026x; 1.0096x over previous
//
#include <hip/hip_runtime.h>
#include <hip/hip_bf16.h>

typedef short short8 __attribute__((ext_vector_type(8)));
typedef float f32x4 __attribute__((ext_vector_type(4)));
typedef const void __attribute__((address_space(1))) as1_void;
typedef void __attribute__((address_space(3))) as3_void;

// hardware trig: input in revolutions (D = sin/cos(S0 * 2pi)), already in [0,1)
__device__ __forceinline__ float sin_rev(float r) {
  float o; asm("v_sin_f32 %0, %1" : "=v"(o) : "v"(r)); return o;
}
__device__ __forceinline__ float cos_rev(float r) {
  float o; asm("v_cos_f32 %0, %1" : "=v"(o) : "v"(r)); return o;
}

#define INV4096 0.000244140625f
#define INV16   0.0625f

// ---------------------------------------------------------------------------
// prep_kernel, grid = 3108 blocks x 256 thr, range-partitioned roles:
//  [0,512)     F2 [512][2048] bf16: row<256: cos(m n), m=row; row>=256: -sin(m n), m=row-255
//  [512,1024)  Gm2 [2048][512] bf16: col<256: cos(n k), k=col; col>=256: +sin(n k), k=col-255
//  [1024,1056) S[b][m] = (t_emb@dense_r + i t_emb@dense_i) * c_m/4096
//  [1056,2080) Hermitian-fold transpose: E[bi][n]=x[n]+x[4096-n], O[bi][n]=x[n]-x[4096-n]
//              (n=0..2047, e'[0]=x[0], o'[0]=0) + Xr256p partials + x2048 row capture
//  [2080,3108) Wb[k][2][4096] bf16 <- {Wr,Wi}[k] fp32
// ---------------------------------------------------------------------------
__global__ __launch_bounds__(256) void prep_kernel(__hip_bfloat16* __restrict__ F2,
                                                   __hip_bfloat16* __restrict__ Gm2,
                                                   const float* __restrict__ t_emb,
                                                   const float* __restrict__ dr,
                                                   const float* __restrict__ di,
                                                   float* __restrict__ Sr,
                                                   float* __restrict__ Si,
                                                   const float* __restrict__ x,
                                                   __hip_bfloat16* __restrict__ E,
                                                   __hip_bfloat16* __restrict__ O,
                                                   float* __restrict__ Xr256p,
                                                   float* __restrict__ x2048f,
                                                   const float* __restrict__ Wr,
                                                   const float* __restrict__ Wi,
                                                   __hip_bfloat16* __restrict__ Wb) {
  const int bid = blockIdx.x;
  const int tid = threadIdx.x;
  __shared__ float te[256];
  __shared__ float tileA[64][65];
  __shared__ float tileB[64][65];
  __shared__ float red[4][64];
  __shared__ float xm[64];

  if (bid < 512) {
    // F2 row = bid, 2048 cols, one short8 per thread
    const int row = bid;
    const int m   = (row < 256) ? row : (row - 255);
    const bool is_cos = (row < 256);
    int n0 = tid * 8;
    union { short8 v; unsigned short u[8]; } pk;
#pragma unroll
    for (int j = 0; j < 8; ++j) {
      int ph = (m * (n0 + j)) & 4095;
      float v = is_cos ?  cos_rev((float)ph * INV4096)
                       : -sin_rev((float)ph * INV4096);
      __hip_bfloat16 h = __float2bfloat16(v);
      pk.u[j] = *(unsigned short*)&h;
    }
    *(short8*)&F2[(size_t)row * 2048 + n0] = pk.v;
  } else if (bid < 1024) {
    // Gm2: 4 n-rows per block, 512 cols each
    const int gb = bid - 512;         // 0..511
    int e  = tid * 8;                 // 0..2047
    int n  = gb * 4 + (e >> 9);
    int c0 = e & 511;
    union { short8 v; unsigned short u[8]; } pk;
#pragma unroll
    for (int j = 0; j < 8; ++j) {
      int cc = c0 + j;
      int k  = (cc < 256) ? cc : (cc - 255);
      int ph = (n * k) & 4095;
      float v = (cc < 256) ? cos_rev((float)ph * INV4096)
                           : sin_rev((float)ph * INV4096);
      __hip_bfloat16 h = __float2bfloat16(v);
      pk.u[j] = *(unsigned short*)&h;
    }
    *(short8*)&Gm2[(size_t)n * 512 + c0] = pk.v;
  } else if (bid < 1056) {
    int b = bid - 1024;   // 0..31
    te[tid] = t_emb[b * 256 + tid];
    __syncthreads();
    for (int m = tid; m < 257; m += 256) {
      float ar = 0.f, ai = 0.f;
      for (int t = 0; t < 256; ++t) {
        float e = te[t];
        ar += e * dr[t * 257 + m];
        ai += e * di[t * 257 + m];
      }
      float c = (m == 0 ? 1.0f : 2.0f) * (1.0f / 4096.0f);
      Sr[b * 257 + m] = ar * c;
      Si[b * 257 + m] = ai * c;
    }
  } else if (bid < 2080) {
    int idx = bid - 1056;         // 0..1023
    int nt = idx & 31;            // n-tile 0..31 (n = nt*64 .. +63)
    int b  = idx >> 5;            // batch
    int n0 = nt * 64;
    int m0r = (63 - nt) * 64;     // mirror tile rows
#pragma unroll
    for (int it = 0; it < 4; ++it) {
      int c = it * 256 + tid;     // 0..1023 float4 chunks
      int r = c >> 4, i4 = (c & 15) * 4;
      float4 v = *(const float4*)&x[((size_t)b * 4096 + n0 + r) * 64 + i4];
      tileA[r][i4 + 0] = v.x; tileA[r][i4 + 1] = v.y;
      tileA[r][i4 + 2] = v.z; tileA[r][i4 + 3] = v.w;
      float4 w = *(const float4*)&x[((size_t)b * 4096 + m0r + r) * 64 + i4];
      tileB[r][i4 + 0] = w.x; tileB[r][i4 + 1] = w.y;
      tileB[r][i4 + 2] = w.z; tileB[r][i4 + 3] = w.w;
    }
    if (tid < 64) xm[tid] = (nt > 0) ? x[((size_t)b * 4096 + (4096 - n0)) * 64 + tid] : 0.f;
    __syncthreads();
    // folded transposed writes: e' = A + mirror, o' = A - mirror
#pragma unroll
    for (int it = 0; it < 2; ++it) {
      int c  = it * 256 + tid;    // 0..511
      int i  = c >> 3;            // 0..63
      int ch = c & 7;             // 8-col chunk
      union { short8 v; unsigned short u[8]; } pe, po;
#pragma unroll
      for (int jj = 0; jj < 8; ++jj) {
        int j = ch * 8 + jj;
        float a = tileA[j][i];
        float mir = (j == 0) ? xm[i] : tileB[64 - j][i];
        __hip_bfloat16 he = __float2bfloat16(a + mir);
        __hip_bfloat16 ho = __float2bfloat16(a - mir);
        pe.u[jj] = *(unsigned short*)&he;
        po.u[jj] = *(unsigned short*)&ho;
      }
      size_t base = ((size_t)b * 64 + i) * 2048 + n0 + ch * 8;
      *(short8*)&E[base] = pe.v;
      *(short8*)&O[base] = po.v;
    }
    // Xr256 partials over BOTH tiles (weight depends on j mod 16 only; 64 = 0 mod 16)
    {
      int i = tid & 63, g = tid >> 6;
      float acc = 0.f;
#pragma unroll
      for (int j = 0; j < 16; ++j) {
        float w = cos_rev((float)j * INV16);
        acc += w * (tileA[g * 16 + j][i] + tileB[g * 16 + j][i]);
      }
      red[g][i] = acc;
    }
    __syncthreads();
    if (tid < 64) {
      Xr256p[((size_t)b * 32 + nt) * 64 + tid] =
          red[0][tid] + red[1][tid] + red[2][tid] + red[3][tid];
      if (nt == 31) x2048f[b * 64 + tid] = tileB[0][tid];   // tileB = tile 32, row 0 = x[2048]
    }
  } else {
    // W fp32 -> bf16 repack
    int idx  = bid - 2080;        // 0..1027
    int k    = idx >> 2;
    int quad = idx & 3;
    const float* src = (quad < 2) ? (Wr + (size_t)k * 4096 + quad * 2048)
                                  : (Wi + (size_t)k * 4096 + (quad - 2) * 2048);
    __hip_bfloat16* dst = Wb + (size_t)k * 8192 + (quad < 2 ? quad * 2048 : 4096 + (quad - 2) * 2048);
    int e = tid * 8;
    float4 v0 = *(const float4*)&src[e];
    float4 v1 = *(const float4*)&src[e + 4];
    union { short8 v; unsigned short u[8]; } pk;
    float vv[8] = {v0.x, v0.y, v0.z, v0.w, v1.x, v1.y, v1.z, v1.w};
#pragma unroll
    for (int j = 0; j < 8; ++j) {
      __hip_bfloat16 h = __float2bfloat16(vv[j]);
      pk.u[j] = *(unsigned short*)&h;
    }
    *(short8*)&dst[e] = pk.v;
  }
}

// ---------------------------------------------------------------------------
// MFMA GEMM core, single-buffer 2-barrier, NF-templated (m97 + T2 pre-swizzle)
// ---------------------------------------------------------------------------
template <int NF>
__device__ __forceinline__ void stage_tileT(const __hip_bfloat16* __restrict__ A, int lda, int m0,
                                            const __hip_bfloat16* __restrict__ B, int ldb, int n0,
                                            int kt, __hip_bfloat16* As, __hip_bfloat16* Bs,
                                            int tid) {
#pragma unroll
  for (int j = 0; j < 4; ++j) {
    int c   = j * 256 + tid;
    int row = c >> 3;
    int chg = (c & 7) ^ (row & 7);
    const __hip_bfloat16* ga = A + (size_t)(m0 + row) * lda + kt + chg * 8;
    __hip_bfloat16* la = As + (size_t)(j * 256 + (tid & 192)) * 8;
    __builtin_amdgcn_global_load_lds((as1_void*)ga, (as3_void*)la, 16, 0, 0);
  }
#pragma unroll
  for (int j = 0; j < NF; ++j) {
    int c   = j * 256 + tid;
    int row = c >> 3;
    int chg = (c & 7) ^ (row & 7);
    const __hip_bfloat16* gb = B + (size_t)(n0 + row) * ldb + kt + chg * 8;
    __hip_bfloat16* lb = Bs + (size_t)(j * 256 + (tid & 192)) * 8;
    __builtin_amdgcn_global_load_lds((as1_void*)gb, (as3_void*)lb, 16, 0, 0);
  }
}

template <int NF>
__device__ __forceinline__ void compute_stepT(const __hip_bfloat16* As, const __hip_bfloat16* Bs,
                                              int wr, int wc, int fr, int fq,
                                              f32x4 acc[4][NF]) {
#pragma unroll
  for (int kk = 0; kk < 2; ++kk) {
    short8 av[4], bv[NF];
#pragma unroll
    for (int m = 0; m < 4; ++m) {
      int row  = wr + m * 16 + fr;
      int slot = (fq + kk * 4) ^ (row & 7);
      av[m] = *(const short8*)(As + row * 64 + slot * 8);
    }
#pragma unroll
    for (int n = 0; n < NF; ++n) {
      int row  = wc + n * 16 + fr;
      int slot = (fq + kk * 4) ^ (row & 7);
      bv[n] = *(const short8*)(Bs + row * 64 + slot * 8);
    }
#pragma unroll
    for (int m = 0; m < 4; ++m)
#pragma unroll
      for (int n = 0; n < NF; ++n)
        acc[m][n] = __builtin_amdgcn_mfma_f32_16x16x32_bf16(av[m], bv[n], acc[m][n], 0, 0, 0);
  }
}

template <int NF>
__device__ __forceinline__ void gemm_coreT(const __hip_bfloat16* __restrict__ A, int lda, int m0,
                                           const __hip_bfloat16* __restrict__ B, int ldb, int n0,
                                           int k0, int ksteps,
                                           __hip_bfloat16* As, __hip_bfloat16* Bs,
                                           f32x4 acc[4][NF]) {
  const int tid  = threadIdx.x;
  const int lane = tid & 63;
  const int wv   = tid >> 6;
  const int wr   = (wv >> 1) * 64;
  const int wc   = (wv & 1) * (NF * 16);
  const int fr   = lane & 15;
  const int fq   = lane >> 4;

  for (int ks = 0; ks < ksteps; ++ks) {
    stage_tileT<NF>(A, lda, m0, B, ldb, n0, k0 + ks * 64, As, Bs, tid);
    __syncthreads();
    compute_stepT<NF>(As, Bs, wr, wc, fr, fq, acc);
    __syncthreads();
  }
}

// GEMM1 (folded): C1[z][row][bi] bf16 = F2 @ {E|O}^T, K=2048
// rows 0..255 (cos) x E ; rows 256..511 (-sin, m=row-255) x O
__global__ __launch_bounds__(256) void gemm1_kernel(const __hip_bfloat16* __restrict__ F2,
                                                    const __hip_bfloat16* __restrict__ E,
                                                    const __hip_bfloat16* __restrict__ O,
                                                    __hip_bfloat16* __restrict__ C1, int kchunk) {
  __shared__ __hip_bfloat16 As[128 * 64];
  __shared__ __hip_bfloat16 Bs[128 * 64];
  int n0 = blockIdx.x * 128;
  int m0 = blockIdx.y * 128;
  int k0 = blockIdx.z * kchunk;
  const __hip_bfloat16* B = (m0 < 256) ? E : O;
  f32x4 acc[4][4];
#pragma unroll
  for (int m = 0; m < 4; ++m)
#pragma unroll
    for (int n = 0; n < 4; ++n)
#pragma unroll
      for (int r = 0; r < 4; ++r) acc[m][n][r] = 0.f;

  gemm_coreT<4>(F2, 2048, m0, B, 2048, n0, k0, kchunk >> 6, As, Bs, acc);

  const int lane = threadIdx.x & 63;
  const int wv   = threadIdx.x >> 6;
  const int wr   = (wv >> 1) * 64, wc = (wv & 1) * 64;
  const int fr   = lane & 15, fq = lane >> 4;
  __hip_bfloat16* P = C1 + (size_t)blockIdx.z * (512 * 2048);
#pragma unroll
  for (int m = 0; m < 4; ++m)
#pragma unroll
    for (int n = 0; n < 4; ++n)
#pragma unroll
      for (int j = 0; j < 4; ++j) {
        int row = m0 + wr + m * 16 + fq * 4 + j;
        int col = n0 + wc + n * 16 + fr;
        P[(size_t)row * 2048 + col] = __float2bfloat16(acc[m][n][j]);
      }
}

// ---------------------------------------------------------------------------
// Mode mix (fused split-K reduce + Hermitian-fold rank-1 correction)
// ---------------------------------------------------------------------------
__global__ __launch_bounds__(256) void mix_kernel(const __hip_bfloat16* __restrict__ C1,
                                                  const float* __restrict__ Xr256p,
                                                  const float* __restrict__ x2048f,
                                                  const __hip_bfloat16* __restrict__ Wb,
                                                  const float* __restrict__ Sr,
                                                  const float* __restrict__ Si,
                                                  __hip_bfloat16* __restrict__ Y2T,
                                                  __hip_bfloat16* __restrict__ Yx,
                                                  int splitk) {
  const int k = blockIdx.x;   // 0..256
  const int q = blockIdx.y;   // 0..3 (batches q*8 .. q*8+7)
  const int tid = threadIdx.x;
  __shared__ float wlr[4096];
  __shared__ float wli[4096];
  __shared__ float xs2[2][1024];
  __shared__ float xs[1024];   // [0..511]=real, [512..1023]=imag; col = bl*64+i

  const __hip_bfloat16* wbg = Wb + (size_t)k * 8192;   // [r 4096][i 4096]
  for (int c = tid; c < 1024; c += 256) {
    short8 v = *(const short8*)(wbg + c * 8);
    float* dst = (c < 512) ? &wlr[c * 8] : &wli[(c - 512) * 8];
#pragma unroll
    for (int j = 0; j < 8; ++j) {
      unsigned short u = (unsigned short)v[j];
      dst[j] = __bfloat162float(*(__hip_bfloat16*)&u);
    }
  }

  const size_t PST = 512ull * 2048;
  if (k < 256) {
    const int zg   = tid >> 7;          // 0..1
    const int part = (tid >> 6) & 1;    // 0=real,1=imag
    const int ln   = tid & 63;
    const int row  = (part == 0) ? k : 255 + k;
    float f[8] = {0.f, 0.f, 0.f, 0.f, 0.f, 0.f, 0.f, 0.f};
    if (part == 0 || k > 0) {
      const __hip_bfloat16* src = C1 + (size_t)row * 2048 + q * 512 + ln * 8;
      const int zh = splitk >> 1;
      for (int z = zg * zh; z < zg * zh + zh; ++z) {
        short8 v = *(const short8*)(src + (size_t)z * PST);
#pragma unroll
        for (int j = 0; j < 8; ++j) {
          unsigned short u = (unsigned short)v[j];
          f[j] += __bfloat162float(*(__hip_bfloat16*)&u);
        }
      }
    }
    if (part == 0 && zg == 0) {
      // fold rank-1 correction: xr += (-1)^k * x[2048][bi]
      float par = (k & 1) ? -1.f : 1.f;
#pragma unroll
      for (int j = 0; j < 8; ++j) f[j] += par * x2048f[q * 512 + ln * 8 + j];
    }
#pragma unroll
    for (int j = 0; j < 8; ++j) xs2[zg][part * 512 + ln * 8 + j] = f[j];
    __syncthreads();
    for (int e = tid; e < 1024; e += 256) xs[e] = xs2[0][e] + xs2[1][e];
  } else {
    // k == 256: real from Xr256p partials (32 slots), imag from C1 row 511
    for (int idx = tid; idx < 1024; idx += 256) {
      int part = idx >> 9;
      int c    = idx & 511;
      float s = 0.f;
      if (part == 0) {
        int bi = q * 512 + c;
        const float* sp = Xr256p + (size_t)(bi >> 6) * 2048 + (bi & 63);
#pragma unroll 8
        for (int nt = 0; nt < 32; ++nt) s += sp[nt * 64];
      } else {
        const __hip_bfloat16* src = C1 + (size_t)511 * 2048 + q * 512 + c;
        for (int z = 0; z < splitk; ++z) s += __bfloat162float(src[(size_t)z * PST]);
      }
      xs[idx] = s;
    }
    __syncthreads();
  }
  __syncthreads();

  const int o  = tid & 63;
  const int jj = tid >> 6;
  const int bl0 = jj * 2, bl1 = jj * 2 + 1;
  float pr0 = 0.f, pi0 = 0.f, pr1 = 0.f, pi1 = 0.f;
#pragma unroll 8
  for (int i = 0; i < 64; ++i) {
    float wrv = wlr[i * 64 + o];
    float wiv = wli[i * 64 + o];
    float xr0 = xs[bl0 * 64 + i], xi0 = xs[512 + bl0 * 64 + i];
    float xr1 = xs[bl1 * 64 + i], xi1 = xs[512 + bl1 * 64 + i];
    pr0 += xr0 * wrv - xi0 * wiv;
    pi0 += xr0 * wiv + xi0 * wrv;
    pr1 += xr1 * wrv - xi1 * wiv;
    pi1 += xr1 * wiv + xi1 * wrv;
  }
  int b0 = q * 8 + bl0, b1 = q * 8 + bl1;
  float sr0 = Sr[b0 * 257 + k], si0 = Si[b0 * 257 + k];
  float sr1 = Sr[b1 * 257 + k], si1 = Si[b1 * 257 + k];
  int bo0 = b0 * 64 + o, bo1 = b1 * 64 + o;
  __hip_bfloat16 yr0 = __float2bfloat16(pr0 * sr0 - pi0 * si0);
  __hip_bfloat16 yi0 = __float2bfloat16(pr0 * si0 + pi0 * sr0);
  __hip_bfloat16 yr1 = __float2bfloat16(pr1 * sr1 - pi1 * si1);
  __hip_bfloat16 yi1 = __float2bfloat16(pr1 * si1 + pi1 * sr1);
  if (k < 256) {
    Y2T[(size_t)bo0 * 512 + k] = yr0;
    Y2T[(size_t)bo1 * 512 + k] = yr1;
  } else {
    Yx[bo0] = yr0;
    Yx[bo1] = yr1;
  }
  if (k >= 1) {
    Y2T[(size_t)bo0 * 512 + 255 + k] = yi0;
    Y2T[(size_t)bo1 * 512 + 255 + k] = yi1;
  }
}

// GEMM2 (folded): rows n=0..2047. accC over cos K-half (+ g*Yx), accS over sin K-half.
// out[n] = accC - accS ; out[4096-n] = accC + accS (n>=1) ; out[2048] = alt-sum (m0==0 blocks)
__global__ __launch_bounds__(256) void gemm2_kernel(const __hip_bfloat16* __restrict__ Gm2,
                                                    const __hip_bfloat16* __restrict__ Y2T,
                                                    const __hip_bfloat16* __restrict__ Yx,
                                                    float* __restrict__ out) {
  __shared__ __hip_bfloat16 As[128 * 64];
  __shared__ __hip_bfloat16 Bs[64 * 64];
  __shared__ float red2[4][64];
  int n0 = blockIdx.x * 64;    // bo
  int m0 = blockIdx.y * 128;   // n (time), 0..1920
  f32x4 accC[4][2], accS[4][2];
#pragma unroll
  for (int m = 0; m < 4; ++m)
#pragma unroll
    for (int n = 0; n < 2; ++n)
#pragma unroll
      for (int r = 0; r < 4; ++r) { accC[m][n][r] = 0.f; accS[m][n][r] = 0.f; }

  gemm_coreT<2>(Gm2, 512, m0, Y2T, 512, n0, 0,   4, As, Bs, accC);
  gemm_coreT<2>(Gm2, 512, m0, Y2T, 512, n0, 256, 4, As, Bs, accS);

  const int lane = threadIdx.x & 63;
  const int wv   = threadIdx.x >> 6;
  const int wr   = (wv >> 1) * 64, wc = (wv & 1) * 32;
  const int fr   = lane & 15, fq = lane >> 4;
  float yx[2];
#pragma unroll
  for (int n = 0; n < 2; ++n)
    yx[n] = __bfloat162float(Yx[n0 + wc + n * 16 + fr]);
#pragma unroll
  for (int m = 0; m < 4; ++m)
#pragma unroll
    for (int j = 0; j < 4; ++j) {
      int row = m0 + wr + m * 16 + fq * 4 + j;   // n index 0..2047
      float g = cos_rev((float)(row & 15) * INV16);
#pragma unroll
      for (int n = 0; n < 2; ++n) {
        int col = n0 + wc + n * 16 + fr;         // bo index
        int b = col >> 6, o = col & 63;
        float vC = accC[m][n][j] + g * yx[n];
        float vS = accS[m][n][j];
        out[((size_t)b * 4096 + row) * 64 + o] = vC - vS;
        if (row > 0)
          out[((size_t)b * 4096 + (4096 - row)) * 64 + o] = vC + vS;
      }
    }

  // out[2048][bo] = sum_k (-1)^k Yr[k] + Yx   (one block column does it)
  if (m0 == 0) {
    __syncthreads();
    const int tid = threadIdx.x;
    int col = tid & 63, grp = tid >> 6;
    int bo = n0 + col;
    float s = 0.f;
    for (int k = grp * 64; k < grp * 64 + 64; ++k) {
      float v = __bfloat162float(Y2T[(size_t)bo * 512 + k]);
      s += (k & 1) ? -v : v;
    }
    red2[grp][col] = s;
    __syncthreads();
    if (tid < 64) {
      int bo2 = n0 + tid;
      float alt = red2[0][tid] + red2[1][tid] + red2[2][tid] + red2[3][tid]
                + __bfloat162float(Yx[bo2]);
      int b = bo2 >> 6, o = bo2 & 63;
      out[((size_t)b * 4096 + 2048) * 64 + o] = alt;
    }
  }
}

// ---------------------------------------------------------------------------
extern "C" void kernel_launch(void* const* d_in, const int* in_sizes, int n_in,
                              void* d_out, int out_size, void* d_ws, size_t ws_size,
                              hipStream_t stream) {
  const float* x  = (const float*)d_in[0];   // (32,4096,64)
  const float* te = (const float*)d_in[1];   // (32,256)
  const float* wr = (const float*)d_in[2];   // (257,64,64)
  const float* wi = (const float*)d_in[3];
  const float* dr = (const float*)d_in[4];   // (256,257)
  const float* di = (const float*)d_in[5];
  float* out = (float*)d_out;

  char* p = (char*)d_ws;
  auto alloc = [&](size_t bytes) -> char* {
    char* r = p;
    p += (bytes + 255) & ~(size_t)255;
    return r;
  };
  __hip_bfloat16* F2  = (__hip_bfloat16*)alloc(512ull * 2048 * 2);
  __hip_bfloat16* Gm2 = (__hip_bfloat16*)alloc(2048ull * 512 * 2);
  __hip_bfloat16* E   = (__hip_bfloat16*)alloc(2048ull * 2048 * 2);
  __hip_bfloat16* O   = (__hip_bfloat16*)alloc(2048ull * 2048 * 2);
  float* Xr256p = (float*)alloc(32ull * 32 * 64 * 4);   // [b][nt 32][i]
  float* x2048f = (float*)alloc(2048 * 4);
  float* Sr = (float*)alloc(32 * 257 * 4);
  float* Si = (float*)alloc(32 * 257 * 4);
  __hip_bfloat16* Y2T = (__hip_bfloat16*)alloc(2048ull * 512 * 2);
  __hip_bfloat16* Yx  = (__hip_bfloat16*)alloc(2048 * 2);
  __hip_bfloat16* Wb  = (__hip_bfloat16*)alloc(257ull * 8192 * 2);
  size_t fixed = (size_t)(p - (char*)d_ws);

  int splitk = 2;
  if (ws_size >= fixed + 8ull * 512 * 2048 * 2)      splitk = 8;
  else if (ws_size >= fixed + 4ull * 512 * 2048 * 2) splitk = 4;
  __hip_bfloat16* C1 = (__hip_bfloat16*)alloc((size_t)splitk * 512 * 2048 * 2);
  int kchunk = 2048 / splitk;

  prep_kernel<<<3108, 256, 0, stream>>>(F2, Gm2, te, dr, di, Sr, Si, x, E, O,
                                        Xr256p, x2048f, wr, wi, Wb);
  gemm1_kernel<<<dim3(16, 4, splitk), 256, 0, stream>>>(F2, E, O, C1, kchunk);
  mix_kernel<<<dim3(257, 4), 256, 0, stream>>>(C1, Xr256p, x2048f, Wb, Sr, Si, Y2T, Yx, splitk);
  gemm2_kernel<<<dim3(32, 16), 256, 0, stream>>>(Gm2, Y2T, Yx, out);
}

// Round 10
// 84.830 us; speedup vs baseline: 1.2598x; 1.0476x over previous
//
#include <hip/hip_runtime.h>
#include <hip/hip_bf16.h>

typedef short short8 __attribute__((ext_vector_type(8)));
typedef float f32x4 __attribute__((ext_vector_type(4)));
typedef const void __attribute__((address_space(1))) as1_void;
typedef void __attribute__((address_space(3))) as3_void;

// hardware trig: input in revolutions (D = sin/cos(S0 * 2pi)), already in [0,1)
__device__ __forceinline__ float sin_rev(float r) {
  float o; asm("v_sin_f32 %0, %1" : "=v"(o) : "v"(r)); return o;
}
__device__ __forceinline__ float cos_rev(float r) {
  float o; asm("v_cos_f32 %0, %1" : "=v"(o) : "v"(r)); return o;
}

#define INV4096 0.000244140625f
#define INV16   0.0625f

// ---------------------------------------------------------------------------
// prep_kernel, grid = 3108 blocks x 256 thr, range-partitioned roles:
//  [0,512)     F2 [512][2048] bf16: row<256: cos(m n), m=row; row>=256: -sin(m n), m=row-255
//  [512,1024)  Gm2 [2048][512] bf16: col<256: cos(n k); col>=256: +sin(n k), k=col-255
//  [1024,1056) S[b][m] = (t_emb@dense_r + i t_emb@dense_i) * c_m/4096
//  [1056,2080) Hermitian-fold transpose: E[bi][n]=x[n]+x[4096-n], O[bi][n]=x[n]-x[4096-n]
//              + Xr256p partials + x2048 row capture
//  [2080,3108) Wb[k][2][4096] bf16 <- {Wr,Wi}[k] fp32
// ---------------------------------------------------------------------------
__global__ __launch_bounds__(256) void prep_kernel(__hip_bfloat16* __restrict__ F2,
                                                   __hip_bfloat16* __restrict__ Gm2,
                                                   const float* __restrict__ t_emb,
                                                   const float* __restrict__ dr,
                                                   const float* __restrict__ di,
                                                   float* __restrict__ Sr,
                                                   float* __restrict__ Si,
                                                   const float* __restrict__ x,
                                                   __hip_bfloat16* __restrict__ E,
                                                   __hip_bfloat16* __restrict__ O,
                                                   float* __restrict__ Xr256p,
                                                   float* __restrict__ x2048f,
                                                   const float* __restrict__ Wr,
                                                   const float* __restrict__ Wi,
                                                   __hip_bfloat16* __restrict__ Wb) {
  const int bid = blockIdx.x;
  const int tid = threadIdx.x;
  __shared__ float te[256];
  __shared__ float tileA[64][65];
  __shared__ float tileB[64][65];
  __shared__ float red[4][64];
  __shared__ float xm[64];

  if (bid < 512) {
    const int row = bid;
    const int m   = (row < 256) ? row : (row - 255);
    const bool is_cos = (row < 256);
    int n0 = tid * 8;
    union { short8 v; unsigned short u[8]; } pk;
#pragma unroll
    for (int j = 0; j < 8; ++j) {
      int ph = (m * (n0 + j)) & 4095;
      float v = is_cos ?  cos_rev((float)ph * INV4096)
                       : -sin_rev((float)ph * INV4096);
      __hip_bfloat16 h = __float2bfloat16(v);
      pk.u[j] = *(unsigned short*)&h;
    }
    *(short8*)&F2[(size_t)row * 2048 + n0] = pk.v;
  } else if (bid < 1024) {
    const int gb = bid - 512;         // 0..511
    int e  = tid * 8;                 // 0..2047
    int n  = gb * 4 + (e >> 9);
    int c0 = e & 511;
    union { short8 v; unsigned short u[8]; } pk;
#pragma unroll
    for (int j = 0; j < 8; ++j) {
      int cc = c0 + j;
      int k  = (cc < 256) ? cc : (cc - 255);
      int ph = (n * k) & 4095;
      float v = (cc < 256) ? cos_rev((float)ph * INV4096)
                           : sin_rev((float)ph * INV4096);
      __hip_bfloat16 h = __float2bfloat16(v);
      pk.u[j] = *(unsigned short*)&h;
    }
    *(short8*)&Gm2[(size_t)n * 512 + c0] = pk.v;
  } else if (bid < 1056) {
    int b = bid - 1024;   // 0..31
    te[tid] = t_emb[b * 256 + tid];
    __syncthreads();
    for (int m = tid; m < 257; m += 256) {
      float ar = 0.f, ai = 0.f;
      for (int t = 0; t < 256; ++t) {
        float e = te[t];
        ar += e * dr[t * 257 + m];
        ai += e * di[t * 257 + m];
      }
      float c = (m == 0 ? 1.0f : 2.0f) * (1.0f / 4096.0f);
      Sr[b * 257 + m] = ar * c;
      Si[b * 257 + m] = ai * c;
    }
  } else if (bid < 2080) {
    int idx = bid - 1056;         // 0..1023
    int nt = idx & 31;            // n-tile 0..31
    int b  = idx >> 5;            // batch
    int n0 = nt * 64;
    int m0r = (63 - nt) * 64;     // mirror tile rows
#pragma unroll
    for (int it = 0; it < 4; ++it) {
      int c = it * 256 + tid;
      int r = c >> 4, i4 = (c & 15) * 4;
      float4 v = *(const float4*)&x[((size_t)b * 4096 + n0 + r) * 64 + i4];
      tileA[r][i4 + 0] = v.x; tileA[r][i4 + 1] = v.y;
      tileA[r][i4 + 2] = v.z; tileA[r][i4 + 3] = v.w;
      float4 w = *(const float4*)&x[((size_t)b * 4096 + m0r + r) * 64 + i4];
      tileB[r][i4 + 0] = w.x; tileB[r][i4 + 1] = w.y;
      tileB[r][i4 + 2] = w.z; tileB[r][i4 + 3] = w.w;
    }
    if (tid < 64) xm[tid] = (nt > 0) ? x[((size_t)b * 4096 + (4096 - n0)) * 64 + tid] : 0.f;
    __syncthreads();
#pragma unroll
    for (int it = 0; it < 2; ++it) {
      int c  = it * 256 + tid;
      int i  = c >> 3;
      int ch = c & 7;
      union { short8 v; unsigned short u[8]; } pe, po;
#pragma unroll
      for (int jj = 0; jj < 8; ++jj) {
        int j = ch * 8 + jj;
        float a = tileA[j][i];
        float mir = (j == 0) ? xm[i] : tileB[64 - j][i];
        __hip_bfloat16 he = __float2bfloat16(a + mir);
        __hip_bfloat16 ho = __float2bfloat16(a - mir);
        pe.u[jj] = *(unsigned short*)&he;
        po.u[jj] = *(unsigned short*)&ho;
      }
      size_t base = ((size_t)b * 64 + i) * 2048 + n0 + ch * 8;
      *(short8*)&E[base] = pe.v;
      *(short8*)&O[base] = po.v;
    }
    {
      int i = tid & 63, g = tid >> 6;
      float acc = 0.f;
#pragma unroll
      for (int j = 0; j < 16; ++j) {
        float w = cos_rev((float)j * INV16);
        acc += w * (tileA[g * 16 + j][i] + tileB[g * 16 + j][i]);
      }
      red[g][i] = acc;
    }
    __syncthreads();
    if (tid < 64) {
      Xr256p[((size_t)b * 32 + nt) * 64 + tid] =
          red[0][tid] + red[1][tid] + red[2][tid] + red[3][tid];
      if (nt == 31) x2048f[b * 64 + tid] = tileB[0][tid];
    }
  } else {
    int idx  = bid - 2080;        // 0..1027
    int k    = idx >> 2;
    int quad = idx & 3;
    const float* src = (quad < 2) ? (Wr + (size_t)k * 4096 + quad * 2048)
                                  : (Wi + (size_t)k * 4096 + (quad - 2) * 2048);
    __hip_bfloat16* dst = Wb + (size_t)k * 8192 + (quad < 2 ? quad * 2048 : 4096 + (quad - 2) * 2048);
    int e = tid * 8;
    float4 v0 = *(const float4*)&src[e];
    float4 v1 = *(const float4*)&src[e + 4];
    union { short8 v; unsigned short u[8]; } pk;
    float vv[8] = {v0.x, v0.y, v0.z, v0.w, v1.x, v1.y, v1.z, v1.w};
#pragma unroll
    for (int j = 0; j < 8; ++j) {
      __hip_bfloat16 h = __float2bfloat16(vv[j]);
      pk.u[j] = *(unsigned short*)&h;
    }
    *(short8*)&dst[e] = pk.v;
  }
}

// ---------------------------------------------------------------------------
// MFMA GEMM core, single-buffer 2-barrier, NF-templated (m97 + T2 pre-swizzle)
// ---------------------------------------------------------------------------
template <int NF>
__device__ __forceinline__ void stage_tileT(const __hip_bfloat16* __restrict__ A, int lda, int m0,
                                            const __hip_bfloat16* __restrict__ B, int ldb, int n0,
                                            int kt, __hip_bfloat16* As, __hip_bfloat16* Bs,
                                            int tid) {
#pragma unroll
  for (int j = 0; j < 4; ++j) {
    int c   = j * 256 + tid;
    int row = c >> 3;
    int chg = (c & 7) ^ (row & 7);
    const __hip_bfloat16* ga = A + (size_t)(m0 + row) * lda + kt + chg * 8;
    __hip_bfloat16* la = As + (size_t)(j * 256 + (tid & 192)) * 8;
    __builtin_amdgcn_global_load_lds((as1_void*)ga, (as3_void*)la, 16, 0, 0);
  }
#pragma unroll
  for (int j = 0; j < NF; ++j) {
    int c   = j * 256 + tid;
    int row = c >> 3;
    int chg = (c & 7) ^ (row & 7);
    const __hip_bfloat16* gb = B + (size_t)(n0 + row) * ldb + kt + chg * 8;
    __hip_bfloat16* lb = Bs + (size_t)(j * 256 + (tid & 192)) * 8;
    __builtin_amdgcn_global_load_lds((as1_void*)gb, (as3_void*)lb, 16, 0, 0);
  }
}

template <int NF>
__device__ __forceinline__ void compute_stepT(const __hip_bfloat16* As, const __hip_bfloat16* Bs,
                                              int wr, int wc, int fr, int fq,
                                              f32x4 acc[4][NF]) {
#pragma unroll
  for (int kk = 0; kk < 2; ++kk) {
    short8 av[4], bv[NF];
#pragma unroll
    for (int m = 0; m < 4; ++m) {
      int row  = wr + m * 16 + fr;
      int slot = (fq + kk * 4) ^ (row & 7);
      av[m] = *(const short8*)(As + row * 64 + slot * 8);
    }
#pragma unroll
    for (int n = 0; n < NF; ++n) {
      int row  = wc + n * 16 + fr;
      int slot = (fq + kk * 4) ^ (row & 7);
      bv[n] = *(const short8*)(Bs + row * 64 + slot * 8);
    }
#pragma unroll
    for (int m = 0; m < 4; ++m)
#pragma unroll
      for (int n = 0; n < NF; ++n)
        acc[m][n] = __builtin_amdgcn_mfma_f32_16x16x32_bf16(av[m], bv[n], acc[m][n], 0, 0, 0);
  }
}

template <int NF>
__device__ __forceinline__ void gemm_coreT(const __hip_bfloat16* __restrict__ A, int lda, int m0,
                                           const __hip_bfloat16* __restrict__ B, int ldb, int n0,
                                           int k0, int ksteps,
                                           __hip_bfloat16* As, __hip_bfloat16* Bs,
                                           f32x4 acc[4][NF]) {
  const int tid  = threadIdx.x;
  const int lane = tid & 63;
  const int wv   = tid >> 6;
  const int wr   = (wv >> 1) * 64;
  const int wc   = (wv & 1) * (NF * 16);
  const int fr   = lane & 15;
  const int fq   = lane >> 4;

  for (int ks = 0; ks < ksteps; ++ks) {
    stage_tileT<NF>(A, lda, m0, B, ldb, n0, k0 + ks * 64, As, Bs, tid);
    __syncthreads();
    compute_stepT<NF>(As, Bs, wr, wc, fr, fq, acc);
    __syncthreads();
  }
}

// GEMM1 (folded): C1[row][z][bi] bf16 = F2 @ {E|O}^T, K=2048.
// NOTE layout: partials for one row are contiguous (row stride = splitk*2048)
__global__ __launch_bounds__(256) void gemm1_kernel(const __hip_bfloat16* __restrict__ F2,
                                                    const __hip_bfloat16* __restrict__ E,
                                                    const __hip_bfloat16* __restrict__ O,
                                                    __hip_bfloat16* __restrict__ C1,
                                                    int kchunk, int splitk) {
  __shared__ __hip_bfloat16 As[128 * 64];
  __shared__ __hip_bfloat16 Bs[128 * 64];
  int n0 = blockIdx.x * 128;
  int m0 = blockIdx.y * 128;
  int k0 = blockIdx.z * kchunk;
  const __hip_bfloat16* B = (m0 < 256) ? E : O;
  f32x4 acc[4][4];
#pragma unroll
  for (int m = 0; m < 4; ++m)
#pragma unroll
    for (int n = 0; n < 4; ++n)
#pragma unroll
      for (int r = 0; r < 4; ++r) acc[m][n][r] = 0.f;

  gemm_coreT<4>(F2, 2048, m0, B, 2048, n0, k0, kchunk >> 6, As, Bs, acc);

  const int lane = threadIdx.x & 63;
  const int wv   = threadIdx.x >> 6;
  const int wr   = (wv >> 1) * 64, wc = (wv & 1) * 64;
  const int fr   = lane & 15, fq = lane >> 4;
#pragma unroll
  for (int m = 0; m < 4; ++m)
#pragma unroll
    for (int n = 0; n < 4; ++n)
#pragma unroll
      for (int j = 0; j < 4; ++j) {
        int row = m0 + wr + m * 16 + fq * 4 + j;
        int col = n0 + wc + n * 16 + fr;
        C1[((size_t)row * splitk + blockIdx.z) * 2048 + col] = __float2bfloat16(acc[m][n][j]);
      }
}

// ---------------------------------------------------------------------------
// Mode mix v3: contiguous per-row split-K reduce, q=2 (16 batches/block),
// bf16 weights staged once, Hermitian-fold rank-1 correction.
// grid (257, 2) x 256 thr
// ---------------------------------------------------------------------------
__global__ __launch_bounds__(256) void mix_kernel(const __hip_bfloat16* __restrict__ C1,
                                                  const float* __restrict__ Xr256p,
                                                  const float* __restrict__ x2048f,
                                                  const __hip_bfloat16* __restrict__ Wb,
                                                  const float* __restrict__ Sr,
                                                  const float* __restrict__ Si,
                                                  __hip_bfloat16* __restrict__ Y2T,
                                                  __hip_bfloat16* __restrict__ Yx,
                                                  int splitk) {
  const int k = blockIdx.x;   // 0..256
  const int q = blockIdx.y;   // 0..1 (batches q*16 .. +16)
  const int tid = threadIdx.x;
  __shared__ float wlr[4096];
  __shared__ float wli[4096];
  __shared__ float xs[2048];   // [0..1023]=real, [1024..2047]=imag; local bi = (b-q*16)*64+i

  // stage weights for mode k: 16 KB bf16 -> fp32 LDS (read ONCE per (k,q))
  const __hip_bfloat16* wbg = Wb + (size_t)k * 8192;
  for (int c = tid; c < 1024; c += 256) {
    short8 v = *(const short8*)(wbg + c * 8);
    float* dst = (c < 512) ? &wlr[c * 8] : &wli[(c - 512) * 8];
#pragma unroll
    for (int j = 0; j < 8; ++j) {
      unsigned short u = (unsigned short)v[j];
      dst[j] = __bfloat162float(*(__hip_bfloat16*)&u);
    }
  }

  // split-K reduce: thread covers 8 contiguous bi of one part; C1 row is
  // contiguous [splitk][2048] -> strides of 4 KB, not 2 MB.
  {
    const int part = tid >> 7;        // 0=real, 1=imag
    const int ln   = tid & 127;       // 8 bi each -> 1024 bi
    const int bi0  = q * 1024 + ln * 8;
    float f[8] = {0.f, 0.f, 0.f, 0.f, 0.f, 0.f, 0.f, 0.f};
    if (k < 256) {
      if (part == 0 || k > 0) {
        int row = part ? 255 + k : k;
        const __hip_bfloat16* src = C1 + (size_t)row * splitk * 2048 + bi0;
        for (int z = 0; z < splitk; ++z) {
          short8 v = *(const short8*)(src + (size_t)z * 2048);
#pragma unroll
          for (int j = 0; j < 8; ++j) {
            unsigned short u = (unsigned short)v[j];
            f[j] += __bfloat162float(*(__hip_bfloat16*)&u);
          }
        }
      }
      if (part == 0) {
        float par = (k & 1) ? -1.f : 1.f;   // cos(k*pi)
#pragma unroll
        for (int j = 0; j < 8; ++j) f[j] += par * x2048f[bi0 + j];
      }
    } else {
      if (part == 0) {
        const float* sp = Xr256p + (size_t)(bi0 >> 6) * 2048 + (bi0 & 63);
#pragma unroll 8
        for (int nt = 0; nt < 32; ++nt)
#pragma unroll
          for (int j = 0; j < 8; ++j) f[j] += sp[nt * 64 + j];
      } else {
        const __hip_bfloat16* src = C1 + (size_t)511 * splitk * 2048 + bi0;
        for (int z = 0; z < splitk; ++z) {
          short8 v = *(const short8*)(src + (size_t)z * 2048);
#pragma unroll
          for (int j = 0; j < 8; ++j) {
            unsigned short u = (unsigned short)v[j];
            f[j] += __bfloat162float(*(__hip_bfloat16*)&u);
          }
        }
      }
    }
#pragma unroll
    for (int j = 0; j < 8; ++j) xs[part * 1024 + ln * 8 + j] = f[j];
  }
  __syncthreads();

  const int o  = tid & 63;
  const int jj = tid >> 6;          // 0..3 -> 4 batches each
  float pr[4] = {0.f, 0.f, 0.f, 0.f};
  float pi[4] = {0.f, 0.f, 0.f, 0.f};
#pragma unroll 4
  for (int i = 0; i < 64; ++i) {
    float wrv = wlr[i * 64 + o];
    float wiv = wli[i * 64 + o];
#pragma unroll
    for (int u = 0; u < 4; ++u) {
      int lb = (jj * 4 + u) * 64 + i;
      float xr = xs[lb], xi = xs[1024 + lb];
      pr[u] += xr * wrv - xi * wiv;
      pi[u] += xr * wiv + xi * wrv;
    }
  }
#pragma unroll
  for (int u = 0; u < 4; ++u) {
    int b = q * 16 + jj * 4 + u;
    float sr = Sr[b * 257 + k], si = Si[b * 257 + k];
    int bo = b * 64 + o;
    __hip_bfloat16 yr = __float2bfloat16(pr[u] * sr - pi[u] * si);
    __hip_bfloat16 yi = __float2bfloat16(pr[u] * si + pi[u] * sr);
    if (k < 256) Y2T[(size_t)bo * 512 + k] = yr;
    else         Yx[bo] = yr;
    if (k >= 1)  Y2T[(size_t)bo * 512 + 255 + k] = yi;
  }
}

// GEMM2 (folded): rows n=0..2047. accC over cos K-half (+ g*Yx), accS over sin K-half.
// out[n] = accC - accS ; out[4096-n] = accC + accS (n>=1) ; out[2048] = alt-sum (m0==0)
__global__ __launch_bounds__(256) void gemm2_kernel(const __hip_bfloat16* __restrict__ Gm2,
                                                    const __hip_bfloat16* __restrict__ Y2T,
                                                    const __hip_bfloat16* __restrict__ Yx,
                                                    float* __restrict__ out) {
  __shared__ __hip_bfloat16 As[128 * 64];
  __shared__ __hip_bfloat16 Bs[64 * 64];
  __shared__ float red2[4][64];
  int n0 = blockIdx.x * 64;    // bo
  int m0 = blockIdx.y * 128;   // n (time), 0..1920
  f32x4 accC[4][2], accS[4][2];
#pragma unroll
  for (int m = 0; m < 4; ++m)
#pragma unroll
    for (int n = 0; n < 2; ++n)
#pragma unroll
      for (int r = 0; r < 4; ++r) { accC[m][n][r] = 0.f; accS[m][n][r] = 0.f; }

  gemm_coreT<2>(Gm2, 512, m0, Y2T, 512, n0, 0,   4, As, Bs, accC);
  gemm_coreT<2>(Gm2, 512, m0, Y2T, 512, n0, 256, 4, As, Bs, accS);

  const int lane = threadIdx.x & 63;
  const int wv   = threadIdx.x >> 6;
  const int wr   = (wv >> 1) * 64, wc = (wv & 1) * 32;
  const int fr   = lane & 15, fq = lane >> 4;
  float yx[2];
#pragma unroll
  for (int n = 0; n < 2; ++n)
    yx[n] = __bfloat162float(Yx[n0 + wc + n * 16 + fr]);
#pragma unroll
  for (int m = 0; m < 4; ++m)
#pragma unroll
    for (int j = 0; j < 4; ++j) {
      int row = m0 + wr + m * 16 + fq * 4 + j;   // n index 0..2047
      float g = cos_rev((float)(row & 15) * INV16);
#pragma unroll
      for (int n = 0; n < 2; ++n) {
        int col = n0 + wc + n * 16 + fr;         // bo index
        int b = col >> 6, o = col & 63;
        float vC = accC[m][n][j] + g * yx[n];
        float vS = accS[m][n][j];
        out[((size_t)b * 4096 + row) * 64 + o] = vC - vS;
        if (row > 0)
          out[((size_t)b * 4096 + (4096 - row)) * 64 + o] = vC + vS;
      }
    }

  if (m0 == 0) {
    __syncthreads();
    const int tid = threadIdx.x;
    int col = tid & 63, grp = tid >> 6;
    int bo = n0 + col;
    float s = 0.f;
    for (int k = grp * 64; k < grp * 64 + 64; ++k) {
      float v = __bfloat162float(Y2T[(size_t)bo * 512 + k]);
      s += (k & 1) ? -v : v;
    }
    red2[grp][col] = s;
    __syncthreads();
    if (tid < 64) {
      int bo2 = n0 + tid;
      float alt = red2[0][tid] + red2[1][tid] + red2[2][tid] + red2[3][tid]
                + __bfloat162float(Yx[bo2]);
      int b = bo2 >> 6, o = bo2 & 63;
      out[((size_t)b * 4096 + 2048) * 64 + o] = alt;
    }
  }
}

// ---------------------------------------------------------------------------
extern "C" void kernel_launch(void* const* d_in, const int* in_sizes, int n_in,
                              void* d_out, int out_size, void* d_ws, size_t ws_size,
                              hipStream_t stream) {
  const float* x  = (const float*)d_in[0];   // (32,4096,64)
  const float* te = (const float*)d_in[1];   // (32,256)
  const float* wr = (const float*)d_in[2];   // (257,64,64)
  const float* wi = (const float*)d_in[3];
  const float* dr = (const float*)d_in[4];   // (256,257)
  const float* di = (const float*)d_in[5];
  float* out = (float*)d_out;

  char* p = (char*)d_ws;
  auto alloc = [&](size_t bytes) -> char* {
    char* r = p;
    p += (bytes + 255) & ~(size_t)255;
    return r;
  };
  __hip_bfloat16* F2  = (__hip_bfloat16*)alloc(512ull * 2048 * 2);
  __hip_bfloat16* Gm2 = (__hip_bfloat16*)alloc(2048ull * 512 * 2);
  __hip_bfloat16* E   = (__hip_bfloat16*)alloc(2048ull * 2048 * 2);
  __hip_bfloat16* O   = (__hip_bfloat16*)alloc(2048ull * 2048 * 2);
  float* Xr256p = (float*)alloc(32ull * 32 * 64 * 4);   // [b][nt 32][i]
  float* x2048f = (float*)alloc(2048 * 4);
  float* Sr = (float*)alloc(32 * 257 * 4);
  float* Si = (float*)alloc(32 * 257 * 4);
  __hip_bfloat16* Y2T = (__hip_bfloat16*)alloc(2048ull * 512 * 2);
  __hip_bfloat16* Yx  = (__hip_bfloat16*)alloc(2048 * 2);
  __hip_bfloat16* Wb  = (__hip_bfloat16*)alloc(257ull * 8192 * 2);
  size_t fixed = (size_t)(p - (char*)d_ws);

  int splitk = 2;
  if (ws_size >= fixed + 8ull * 512 * 2048 * 2)      splitk = 8;
  else if (ws_size >= fixed + 4ull * 512 * 2048 * 2) splitk = 4;
  __hip_bfloat16* C1 = (__hip_bfloat16*)alloc((size_t)splitk * 512 * 2048 * 2);
  int kchunk = 2048 / splitk;

  prep_kernel<<<3108, 256, 0, stream>>>(F2, Gm2, te, dr, di, Sr, Si, x, E, O,
                                        Xr256p, x2048f, wr, wi, Wb);
  gemm1_kernel<<<dim3(16, 4, splitk), 256, 0, stream>>>(F2, E, O, C1, kchunk, splitk);
  mix_kernel<<<dim3(257, 2), 256, 0, stream>>>(C1, Xr256p, x2048f, Wb, Sr, Si, Y2T, Yx, splitk);
  gemm2_kernel<<<dim3(32, 16), 256, 0, stream>>>(Gm2, Y2T, Yx, out);
}